// Round 1
// baseline (924.537 us; speedup 1.0000x reference)
//
#include <hip/hip_runtime.h>
#include <hip/hip_bf16.h>

typedef __attribute__((ext_vector_type(8))) short short8;
typedef __attribute__((ext_vector_type(4))) float f32x4;
typedef unsigned short u16;
typedef unsigned int u32;

#define NTOK   8192
#define DMODEL 1024
#define DFF    4096
#define NEXP   8
#define NPAIR  (NTOK * 2)
#define BM     128
#define BN     64
#define BKC    64
#define MT     136            // ceil((16384 + 8*127)/128)
#define PPAD   (MT * BM)      // 17408

// ---- workspace layout (bytes) ----
#define OFF_XB   0ull
#define OFF_W1T  (OFF_XB  + (size_t)NTOK * DMODEL * 2)        //  16,777,216
#define OFF_W2T  (OFF_W1T + (size_t)NEXP * DFF * DMODEL * 2)  //  83,886,080
#define OFF_W3T  (OFF_W2T + (size_t)NEXP * DFF * DMODEL * 2)  // 150,994,944
#define OFF_H    (OFF_W3T + (size_t)NEXP * DMODEL * DFF * 2)  // 218,103,808
#define OFF_TOK  (OFF_H   + (size_t)PPAD * DFF * 2)           // 360,710,144
#define OFF_WGT  (OFF_TOK + (size_t)PPAD * 4)
#define OFF_CNT  (OFF_WGT + (size_t)PPAD * 4)
#define OFF_CUR  (OFF_CNT + 64)
#define OFF_OFFP (OFF_CUR + 64)
#define WS_END   (OFF_OFFP + 64)

#define GLOAD16(gp, lp)                                                        \
  __builtin_amdgcn_global_load_lds(                                            \
      (const __attribute__((address_space(1))) u32*)(gp),                      \
      (__attribute__((address_space(3))) u32*)(lp), 16, 0, 0)

__device__ __forceinline__ u16 f2bu(float f) {
  __hip_bfloat16 b = __float2bfloat16(f);
  return __builtin_bit_cast(u16, b);
}

// ---------------- conversion kernels ----------------

__global__ __launch_bounds__(256) void cvt_x_k(const float* __restrict__ x,
                                               u16* __restrict__ xb) {
  int i = blockIdx.x * 256 + threadIdx.x;            // 2M threads, 4 elems each
  float4 v = ((const float4*)x)[i];
  unsigned long long pk = (unsigned long long)f2bu(v.x) |
                          ((unsigned long long)f2bu(v.y) << 16) |
                          ((unsigned long long)f2bu(v.z) << 32) |
                          ((unsigned long long)f2bu(v.w) << 48);
  ((unsigned long long*)xb)[i] = pk;
}

// transpose [R][C] fp32 -> [C][R] bf16, batched over blockIdx.z
__global__ __launch_bounds__(256) void tr_cvt_k(const float* __restrict__ src,
                                                u16* __restrict__ dst, int R, int C) {
  src += (size_t)blockIdx.z * R * C;
  dst += (size_t)blockIdx.z * R * C;
  int c0 = blockIdx.x * 64, r0 = blockIdx.y * 64;
  __shared__ float tile[64][65];
  int tid = threadIdx.x;
  int f4 = tid & 15, rr = tid >> 4;
#pragma unroll
  for (int p = 0; p < 4; ++p) {
    int r = rr + p * 16;
    float4 v = *(const float4*)(src + (size_t)(r0 + r) * C + c0 + f4 * 4);
    tile[r][f4 * 4 + 0] = v.x; tile[r][f4 * 4 + 1] = v.y;
    tile[r][f4 * 4 + 2] = v.z; tile[r][f4 * 4 + 3] = v.w;
  }
  __syncthreads();
  int ch = tid & 7, cc = tid >> 3;
#pragma unroll
  for (int p = 0; p < 2; ++p) {
    int c = cc + p * 32;
    short8 s;
#pragma unroll
    for (int j = 0; j < 8; ++j) s[j] = (short)f2bu(tile[ch * 8 + j][c]);
    *(short8*)(dst + (size_t)(c0 + c) * R + r0 + ch * 8) = s;
  }
}

// ---------------- routing kernels ----------------

__global__ __launch_bounds__(256) void count_k(const int* __restrict__ ei,
                                               int* __restrict__ cnt) {
  int i = blockIdx.x * 256 + threadIdx.x;            // exactly NPAIR threads
  atomicAdd(&cnt[ei[i]], 1);
}

__global__ void scan_k(const int* __restrict__ cnt, int* __restrict__ offp) {
  if (threadIdx.x == 0) {
    int a = 0;
#pragma unroll
    for (int e = 0; e < NEXP; ++e) { offp[e] = a; a += (cnt[e] + BM - 1) & ~(BM - 1); }
    offp[NEXP] = a;
  }
}

__global__ __launch_bounds__(256) void scatter_k(const int* __restrict__ ei,
                                                 const float* __restrict__ ew,
                                                 const int* __restrict__ offp,
                                                 int* __restrict__ cur,
                                                 int* __restrict__ tok,
                                                 float* __restrict__ wg) {
  int i = blockIdx.x * 256 + threadIdx.x;
  int e = ei[i];
  int p = offp[e] + atomicAdd(&cur[e], 1);
  tok[p] = i >> 1;
  wg[p] = ew[i];
}

// ---------------- stage 1: h = silu(x@W1) * (x@W2), grouped ----------------

__global__ __launch_bounds__(256) void stage1_k(const u16* __restrict__ xb,
                                                const u16* __restrict__ w1t,
                                                const u16* __restrict__ w2t,
                                                u16* __restrict__ h,
                                                const int* __restrict__ tok,
                                                const int* __restrict__ offp) {
  __shared__ __align__(16) u16 As[BM * BKC];
  __shared__ __align__(16) u16 B1s[BN * BKC];
  __shared__ __align__(16) u16 B2s[BN * BKC];
  const int r0 = blockIdx.y * BM;
  if (r0 >= offp[NEXP]) return;
  int e = 0;
#pragma unroll
  for (int q = 0; q < 7; ++q) e += (offp[e + 1] <= r0) ? 1 : 0;
  const int n0 = blockIdx.x * BN;
  const int tid = threadIdx.x;
  const int lane = tid & 63, w = tid >> 6;
  const int wm = w >> 1, wn = w & 1;
  const int lr = lane >> 3, seg = lane & 7;

  // staging source pointers (source-side XOR swizzle, LDS dest linear)
  const u16* aga[4];
#pragma unroll
  for (int j = 0; j < 4; ++j) {
    int rowl = w * 32 + j * 8 + lr;
    int t = tok[r0 + rowl];
    aga[j] = xb + (size_t)t * DMODEL + ((seg ^ (rowl & 7)) << 3);
  }
  const u16* w1e = w1t + (size_t)e * DFF * DMODEL;
  const u16* w2e = w2t + (size_t)e * DFF * DMODEL;
  const u16* bga1[2]; const u16* bga2[2];
#pragma unroll
  for (int j = 0; j < 2; ++j) {
    int coll = w * 16 + j * 8 + lr;
    size_t ro = (size_t)(n0 + coll) * DMODEL + ((seg ^ (coll & 7)) << 3);
    bga1[j] = w1e + ro; bga2[j] = w2e + ro;
  }
  u16 *Ad[4], *B1d[2], *B2d[2];
#pragma unroll
  for (int j = 0; j < 4; ++j) Ad[j] = As + (w * 32 + j * 8) * BKC;
#pragma unroll
  for (int j = 0; j < 2; ++j) { B1d[j] = B1s + (w * 16 + j * 8) * BKC;
                                B2d[j] = B2s + (w * 16 + j * 8) * BKC; }

  int aoff[4][2], boff[2][2];
  {
    int ar = wm * 64 + (lane & 15), ks = lane >> 4;
#pragma unroll
    for (int mi = 0; mi < 4; ++mi)
#pragma unroll
      for (int kk = 0; kk < 2; ++kk) {
        int row = ar + mi * 16;
        aoff[mi][kk] = row * BKC + (((kk * 4 + ks) ^ (row & 7)) << 3);
      }
    int bc = wn * 32 + (lane & 15);
#pragma unroll
    for (int ni = 0; ni < 2; ++ni)
#pragma unroll
      for (int kk = 0; kk < 2; ++kk) {
        int col = bc + ni * 16;
        boff[ni][kk] = col * BKC + (((kk * 4 + ks) ^ (col & 7)) << 3);
      }
  }

  f32x4 accg[4][2], accv[4][2];
  const f32x4 zero = {0.f, 0.f, 0.f, 0.f};
#pragma unroll
  for (int mi = 0; mi < 4; ++mi)
#pragma unroll
    for (int ni = 0; ni < 2; ++ni) { accg[mi][ni] = zero; accv[mi][ni] = zero; }

  for (int kc = 0; kc < DMODEL / BKC; ++kc) {
    const int ko = kc * BKC;
#pragma unroll
    for (int j = 0; j < 4; ++j) GLOAD16(aga[j] + ko, Ad[j]);
#pragma unroll
    for (int j = 0; j < 2; ++j) { GLOAD16(bga1[j] + ko, B1d[j]);
                                  GLOAD16(bga2[j] + ko, B2d[j]); }
    __syncthreads();
#pragma unroll
    for (int kk = 0; kk < 2; ++kk) {
      short8 a[4], b1[2], b2[2];
#pragma unroll
      for (int mi = 0; mi < 4; ++mi) a[mi] = *(const short8*)(As + aoff[mi][kk]);
#pragma unroll
      for (int ni = 0; ni < 2; ++ni) { b1[ni] = *(const short8*)(B1s + boff[ni][kk]);
                                       b2[ni] = *(const short8*)(B2s + boff[ni][kk]); }
#pragma unroll
      for (int mi = 0; mi < 4; ++mi)
#pragma unroll
        for (int ni = 0; ni < 2; ++ni) {
          accg[mi][ni] = __builtin_amdgcn_mfma_f32_16x16x32_bf16(a[mi], b1[ni], accg[mi][ni], 0, 0, 0);
          accv[mi][ni] = __builtin_amdgcn_mfma_f32_16x16x32_bf16(a[mi], b2[ni], accv[mi][ni], 0, 0, 0);
        }
    }
    __syncthreads();
  }

  const int prow = r0 + wm * 64 + ((lane >> 4) << 2);
  const int pcol = n0 + wn * 32 + (lane & 15);
#pragma unroll
  for (int mi = 0; mi < 4; ++mi)
#pragma unroll
    for (int ni = 0; ni < 2; ++ni)
#pragma unroll
      for (int j = 0; j < 4; ++j) {
        float g = accg[mi][ni][j];
        float v = accv[mi][ni][j];
        float s = g / (1.f + __expf(-g));       // silu(g)
        h[(size_t)(prow + mi * 16 + j) * DFF + (pcol + ni * 16)] = f2bu(s * v);
      }
}

// ---------------- stage 2: out += p * (h @ W3), grouped ----------------

__global__ __launch_bounds__(256) void stage2_k(const u16* __restrict__ h,
                                                const u16* __restrict__ w3t,
                                                float* __restrict__ out,
                                                const int* __restrict__ tok,
                                                const float* __restrict__ wg,
                                                const int* __restrict__ offp) {
  __shared__ __align__(16) u16 As[BM * BKC];
  __shared__ __align__(16) u16 Bs[BN * BKC];
  const int r0 = blockIdx.y * BM;
  if (r0 >= offp[NEXP]) return;
  int e = 0;
#pragma unroll
  for (int q = 0; q < 7; ++q) e += (offp[e + 1] <= r0) ? 1 : 0;
  const int n0 = blockIdx.x * BN;
  const int tid = threadIdx.x;
  const int lane = tid & 63, w = tid >> 6;
  const int wm = w >> 1, wn = w & 1;
  const int lr = lane >> 3, seg = lane & 7;

  const u16* aga[4];
#pragma unroll
  for (int j = 0; j < 4; ++j) {
    int rowl = w * 32 + j * 8 + lr;
    aga[j] = h + (size_t)(r0 + rowl) * DFF + ((seg ^ (rowl & 7)) << 3);
  }
  const u16* w3e = w3t + (size_t)e * DMODEL * DFF;
  const u16* bga[2];
#pragma unroll
  for (int j = 0; j < 2; ++j) {
    int coll = w * 16 + j * 8 + lr;
    bga[j] = w3e + (size_t)(n0 + coll) * DFF + ((seg ^ (coll & 7)) << 3);
  }
  u16 *Ad[4], *Bd[2];
#pragma unroll
  for (int j = 0; j < 4; ++j) Ad[j] = As + (w * 32 + j * 8) * BKC;
#pragma unroll
  for (int j = 0; j < 2; ++j) Bd[j] = Bs + (w * 16 + j * 8) * BKC;

  int aoff[4][2], boff[2][2];
  {
    int ar = wm * 64 + (lane & 15), ks = lane >> 4;
#pragma unroll
    for (int mi = 0; mi < 4; ++mi)
#pragma unroll
      for (int kk = 0; kk < 2; ++kk) {
        int row = ar + mi * 16;
        aoff[mi][kk] = row * BKC + (((kk * 4 + ks) ^ (row & 7)) << 3);
      }
    int bc = wn * 32 + (lane & 15);
#pragma unroll
    for (int ni = 0; ni < 2; ++ni)
#pragma unroll
      for (int kk = 0; kk < 2; ++kk) {
        int col = bc + ni * 16;
        boff[ni][kk] = col * BKC + (((kk * 4 + ks) ^ (col & 7)) << 3);
      }
  }

  f32x4 acc[4][2];
  const f32x4 zero = {0.f, 0.f, 0.f, 0.f};
#pragma unroll
  for (int mi = 0; mi < 4; ++mi)
#pragma unroll
    for (int ni = 0; ni < 2; ++ni) acc[mi][ni] = zero;

  for (int kc = 0; kc < DFF / BKC; ++kc) {
    const int ko = kc * BKC;
#pragma unroll
    for (int j = 0; j < 4; ++j) GLOAD16(aga[j] + ko, Ad[j]);
#pragma unroll
    for (int j = 0; j < 2; ++j) GLOAD16(bga[j] + ko, Bd[j]);
    __syncthreads();
#pragma unroll
    for (int kk = 0; kk < 2; ++kk) {
      short8 a[4], b[2];
#pragma unroll
      for (int mi = 0; mi < 4; ++mi) a[mi] = *(const short8*)(As + aoff[mi][kk]);
#pragma unroll
      for (int ni = 0; ni < 2; ++ni) b[ni] = *(const short8*)(Bs + boff[ni][kk]);
#pragma unroll
      for (int mi = 0; mi < 4; ++mi)
#pragma unroll
        for (int ni = 0; ni < 2; ++ni)
          acc[mi][ni] = __builtin_amdgcn_mfma_f32_16x16x32_bf16(a[mi], b[ni], acc[mi][ni], 0, 0, 0);
    }
    __syncthreads();
  }

  const int prow = r0 + wm * 64 + ((lane >> 4) << 2);
  const int pcol = n0 + wn * 32 + (lane & 15);
#pragma unroll
  for (int mi = 0; mi < 4; ++mi)
#pragma unroll
    for (int j = 0; j < 4; ++j) {
      int pos = prow + mi * 16 + j;
      float p = wg[pos];
      if (p != 0.f) {
        int t = tok[pos];
#pragma unroll
        for (int ni = 0; ni < 2; ++ni)
          atomicAdd(&out[(size_t)t * DMODEL + pcol + ni * 16], p * acc[mi][ni][j]);
      }
    }
}

// ---------------- launch ----------------

extern "C" void kernel_launch(void* const* d_in, const int* in_sizes, int n_in,
                              void* d_out, int out_size, void* d_ws, size_t ws_size,
                              hipStream_t stream) {
  (void)in_sizes; (void)n_in;
  const float* x  = (const float*)d_in[0];
  const int*   ei = (const int*)d_in[1];
  const float* ew = (const float*)d_in[2];
  const float* w1 = (const float*)d_in[3];
  const float* w2 = (const float*)d_in[4];
  const float* w3 = (const float*)d_in[5];
  float* out = (float*)d_out;
  char* ws = (char*)d_ws;

  hipMemsetAsync(out, 0, (size_t)out_size * sizeof(float), stream);
  if (ws_size < WS_END) return;   // ws too small: leave zeros (diagnosable absmax)

  u16* xb   = (u16*)(ws + OFF_XB);
  u16* w1t  = (u16*)(ws + OFF_W1T);
  u16* w2t  = (u16*)(ws + OFF_W2T);
  u16* w3t  = (u16*)(ws + OFF_W3T);
  u16* hb   = (u16*)(ws + OFF_H);
  int* tok  = (int*)(ws + OFF_TOK);
  float* wg = (float*)(ws + OFF_WGT);
  int* cnt  = (int*)(ws + OFF_CNT);
  int* cur  = (int*)(ws + OFF_CUR);
  int* offp = (int*)(ws + OFF_OFFP);

  hipMemsetAsync(ws + OFF_TOK, 0, (size_t)(WS_END - OFF_TOK), stream);

  cvt_x_k<<<dim3(NTOK * DMODEL / 4 / 256), 256, 0, stream>>>(x, xb);
  tr_cvt_k<<<dim3(DFF / 64, DMODEL / 64, NEXP), 256, 0, stream>>>(w1, w1t, DMODEL, DFF);
  tr_cvt_k<<<dim3(DFF / 64, DMODEL / 64, NEXP), 256, 0, stream>>>(w2, w2t, DMODEL, DFF);
  tr_cvt_k<<<dim3(DMODEL / 64, DFF / 64, NEXP), 256, 0, stream>>>(w3, w3t, DFF, DMODEL);
  count_k<<<dim3(NPAIR / 256), 256, 0, stream>>>(ei, cnt);
  scan_k<<<1, 64, 0, stream>>>(cnt, offp);
  scatter_k<<<dim3(NPAIR / 256), 256, 0, stream>>>(ei, ew, offp, cur, tok, wg);
  stage1_k<<<dim3(DFF / BN, MT), 256, 0, stream>>>(xb, w1t, w2t, hb, tok, offp);
  stage2_k<<<dim3(DMODEL / BN, MT), 256, 0, stream>>>(hb, w3t, out, tok, wg, offp);
}